// Round 6
// baseline (138.064 us; speedup 1.0000x reference)
//
#include <hip/hip_runtime.h>
#include <hip/hip_bf16.h>
#include <cstdint>
#include <cstddef>

// SelfAttentionV2: x[4096,1024] fp32; Wq/Wk/Wv [1024,1024] fp32.
// out = softmax(causal((x Wq^T)(x Wk^T)^T / 32)) @ (x Wv^T), fp32 out.
//
// Pipeline (all bf16 MFMA):
//   cvt_all:  x->xb bf16, W->Wcat bf16 (Wq scaled by 1/32), one fused launch
//   gemm_qkv: C[4096,3072] = xb @ Wcat^T -> Qb,Kb row-major bf16; V transposed (Vt[1024][4096])
//   gemm_qkt: S = Qb @ Kb^T, lower-triangle tiles only, diag masked with -inf, bf16
//   softmax:  row softmax over causal prefix, in place, bf16 P
//   gemm_pv_split: out = P @ Vt^T, split-K; chunk0 -> out, chunks>=1 -> fp32 partials
//   reduce_pv: out[rows>=1024] += partials
//
// GEMM main loop: 128x128 tile, BK=32, TRIPLE-buffered LDS (48KB -> 3 blocks/CU),
// depth-2 prefetch with counted vmcnt(8): step s issues loads for s+2; the 8
// outstanding younger loads belong to s+1,s+2, so vmcnt(8) = "step s's data
// landed" while every load ages ~2 compute windows (covers L2/HBM latency).
// Write-hazard proof: step s writes buf[(s+2)%3] = buffer read at s-1; all
// reads of s-1 completed (lgkmcnt(0)) before barrier#2(s-1), which every wave
// passed before entering step s.
// LDS rows 64B; XOR swizzle byte ^= ((row>>3)&1)<<5 applied to the global
// SOURCE on stage (global_load_lds writes linearly) and to the ds_read addr.

#define SEQQ 4096
#define DDIM 1024

typedef __bf16 bf16x8 __attribute__((ext_vector_type(8)));
typedef float f32x4 __attribute__((ext_vector_type(4)));

__device__ __forceinline__ unsigned short f2bf(float f) {
  unsigned int u = __builtin_bit_cast(unsigned int, f);
  unsigned int r = u + 0x7FFFu + ((u >> 16) & 1u);  // RNE; -inf stays -inf
  return (unsigned short)(r >> 16);
}

__device__ __forceinline__ void gload_lds16(const void* g, void* lds) {
  __builtin_amdgcn_global_load_lds(
      (__attribute__((address_space(1))) void*)(uintptr_t)g,
      (__attribute__((address_space(3))) void*)(uintptr_t)lds, 16, 0, 0);
}

// ---- fused fp32 -> bf16 conversion (x, Wq*1/32, Wk, Wv) ----
__global__ __launch_bounds__(256) void cvt_all(const float* __restrict__ x,
                                               const float* __restrict__ Wq,
                                               const float* __restrict__ Wk,
                                               const float* __restrict__ Wv,
                                               unsigned short* __restrict__ xb,
                                               unsigned short* __restrict__ Wcat) {
  int b = blockIdx.x;
  const float* src;
  unsigned short* dst;
  float scale = 1.0f;
  if (b < 4096) {
    src = x; dst = xb;
  } else if (b < 5120) {
    src = Wq; dst = Wcat; scale = 0.03125f; b -= 4096;
  } else if (b < 6144) {
    src = Wk; dst = Wcat + (1u << 20); b -= 5120;
  } else {
    src = Wv; dst = Wcat + (2u << 20); b -= 6144;
  }
  const int i = (b * 256 + threadIdx.x) * 4;
  const float4 v = *reinterpret_cast<const float4*>(src + i);
  ushort4 o;
  o.x = f2bf(v.x * scale);
  o.y = f2bf(v.y * scale);
  o.z = f2bf(v.z * scale);
  o.w = f2bf(v.w * scale);
  *reinterpret_cast<ushort4*>(dst + i) = o;
}

// ---- GEMM building blocks: 128x128 tile, BK=32, 4 waves, 3x LDS buffers ----
// LDS tile [128][32] bf16 (64B rows), 8KB per operand per buffer.
// Stage: 8 chunks of 1KB (16 rows each); chunk c = wave*2+i, lane l writes
// row c*16 + l/4, source col byte ((l&3)*16) ^ (((row>>3)&1)<<5).

__device__ __forceinline__ void stage_init32(const unsigned short* gtile, size_t ld,
                                             const char* p[2], int wave, int lane) {
#pragma unroll
  for (int i = 0; i < 2; ++i) {
    const int c = wave * 2 + i;
    const int row = c * 16 + (lane >> 2);
    const int kb = ((lane & 3) * 16) ^ (((row >> 3) & 1) << 5);
    p[i] = (const char*)gtile + (size_t)row * (ld * 2) + kb;
  }
}

__device__ __forceinline__ void stage_issue32(const char* p[2], unsigned short* lds,
                                              int wave) {
#pragma unroll
  for (int i = 0; i < 2; ++i)
    gload_lds16(p[i], (char*)lds + (wave * 2 + i) * 1024);
}

// Swizzled frag addresses relative to buffer 0 (add 4096*buf elems for others).
__device__ __forceinline__ void frag_addrs32(const unsigned short* lds, int wrow, int lane,
                                             const unsigned short* fa[4]) {
  const int rbase = wrow + (lane & 15);
  const int kb = (lane >> 4) * 16;
#pragma unroll
  for (int m = 0; m < 4; ++m) {
    int off = ((rbase + m * 16) << 6) + kb;
    off ^= ((off >> 9) & 1) << 5;
    fa[m] = (const unsigned short*)((const char*)lds + off);
  }
}

#define GEMM_PREAMBLE()                                                     \
  __shared__ unsigned short As[3][4096] __attribute__((aligned(16)));       \
  __shared__ unsigned short Bs[3][4096] __attribute__((aligned(16)));       \
  const int tid = threadIdx.x;                                              \
  const int wave = tid >> 6, lane = tid & 63;                               \
  const int wr = (wave >> 1) * 64, wc = (wave & 1) * 64;                    \
  f32x4 acc[4][4] = {};

// K loop over BK=32 steps [S0,S1); step s covers elems [s*32, s*32+32).
// 3-deep ring, depth-2 prefetch, counted vmcnt(8)/(4)/(0).
#define GEMM_LOOP(ABASE, LDA, BBASE, LDB, S0, S1)                           \
  do {                                                                      \
    const char* pa[2];                                                      \
    const char* pb[2];                                                      \
    stage_init32((ABASE) + (size_t)(S0) * 32, (LDA), pa, wave, lane);       \
    stage_init32((BBASE) + (size_t)(S0) * 32, (LDB), pb, wave, lane);       \
    const unsigned short* fa[4];                                            \
    const unsigned short* fb[4];                                            \
    frag_addrs32(As[0], wr, lane, fa);                                      \
    frag_addrs32(Bs[0], wc, lane, fb);                                      \
    stage_issue32(pa, As[0], wave);                                         \
    stage_issue32(pb, Bs[0], wave);                                         \
    if ((S0) + 1 < (S1)) {                                                  \
      _Pragma("unroll")                                                     \
      for (int i = 0; i < 2; ++i) { pa[i] += 64; pb[i] += 64; }             \
      stage_issue32(pa, As[1], wave);                                       \
      stage_issue32(pb, Bs[1], wave);                                       \
    }                                                                       \
    int rb = 0;                                                             \
    for (int s = (S0); s < (S1); ++s) {                                     \
      if (s + 2 < (S1)) {                                                   \
        const int wb = (rb + 2 >= 3) ? rb - 1 : rb + 2;                     \
        _Pragma("unroll")                                                   \
        for (int i = 0; i < 2; ++i) { pa[i] += 64; pb[i] += 64; }           \
        stage_issue32(pa, &As[0][wb * 4096], wave);                         \
        stage_issue32(pb, &Bs[0][wb * 4096], wave);                         \
        asm volatile("s_waitcnt vmcnt(8)" ::: "memory");                    \
      } else if (s + 1 < (S1)) {                                            \
        asm volatile("s_waitcnt vmcnt(4)" ::: "memory");                    \
      } else {                                                              \
        asm volatile("s_waitcnt vmcnt(0)" ::: "memory");                    \
      }                                                                     \
      asm volatile("s_barrier" ::: "memory");                               \
      const int off = rb * 4096;                                            \
      bf16x8 a[4], b[4];                                                    \
      _Pragma("unroll")                                                     \
      for (int m = 0; m < 4; ++m) {                                         \
        a[m] = *reinterpret_cast<const bf16x8*>(fa[m] + off);               \
        b[m] = *reinterpret_cast<const bf16x8*>(fb[m] + off);               \
      }                                                                     \
      _Pragma("unroll")                                                     \
      for (int m = 0; m < 4; ++m)                                           \
        _Pragma("unroll")                                                   \
        for (int n = 0; n < 4; ++n)                                         \
          acc[m][n] = __builtin_amdgcn_mfma_f32_16x16x32_bf16(              \
              a[m], b[n], acc[m][n], 0, 0, 0);                              \
      asm volatile("s_waitcnt lgkmcnt(0)" ::: "memory");                    \
      asm volatile("s_barrier" ::: "memory");                               \
      rb = (rb == 2) ? 0 : rb + 1;                                          \
    }                                                                       \
  } while (0)

// ---- QKV: C[4096,3072] = xb @ Wcat^T; Q,K row-major; V transposed ----
__global__ __launch_bounds__(256, 3) void gemm_qkv(const unsigned short* __restrict__ X,
                                                   const unsigned short* __restrict__ W,
                                                   unsigned short* __restrict__ Qb,
                                                   unsigned short* __restrict__ Kb,
                                                   unsigned short* __restrict__ Vt) {
  GEMM_PREAMBLE();
  const int brow = blockIdx.y * 128, bcol = blockIdx.x * 128;
  GEMM_LOOP(X + (size_t)brow * DDIM, DDIM, W + (size_t)bcol * DDIM, DDIM, 0, 32);
  const int region = bcol >> 10;  // 0=Q 1=K 2=V
  const int lcol = bcol & 1023;
  const int c0 = wc + (lane & 15);
  const int r0 = wr + ((lane >> 4) << 2);
  if (region < 2) {
    unsigned short* dst = (region == 0) ? Qb : Kb;
#pragma unroll
    for (int m = 0; m < 4; ++m) {
      const int r = brow + r0 + m * 16;
#pragma unroll
      for (int n = 0; n < 4; ++n) {
        const int c = lcol + c0 + n * 16;
#pragma unroll
        for (int j = 0; j < 4; ++j)
          dst[(size_t)(r + j) * DDIM + c] = f2bf(acc[m][n][j]);
      }
    }
  } else {
#pragma unroll
    for (int m = 0; m < 4; ++m) {
      const int r = brow + r0 + m * 16;
#pragma unroll
      for (int n = 0; n < 4; ++n) {
        const int c = lcol + c0 + n * 16;
        ushort4 pk;
        pk.x = f2bf(acc[m][n][0]);
        pk.y = f2bf(acc[m][n][1]);
        pk.z = f2bf(acc[m][n][2]);
        pk.w = f2bf(acc[m][n][3]);
        *reinterpret_cast<ushort4*>(Vt + (size_t)c * SEQQ + r) = pk;
      }
    }
  }
}

// ---- QK^T: S = Qb @ Kb^T, lower-triangle tiles, causal mask on diag ----
__global__ __launch_bounds__(256, 3) void gemm_qkt(const unsigned short* __restrict__ Qb,
                                                   const unsigned short* __restrict__ Kb,
                                                   unsigned short* __restrict__ S) {
  const int bi = blockIdx.y, bj = blockIdx.x;
  if (bj > bi) return;  // upper-triangle tiles never computed nor read
  GEMM_PREAMBLE();
  const int brow = bi * 128, bcol = bj * 128;
  GEMM_LOOP(Qb + (size_t)brow * DDIM, DDIM, Kb + (size_t)bcol * DDIM, DDIM, 0, 32);
  const int c0 = wc + (lane & 15);
  const int r0 = wr + ((lane >> 4) << 2);
#pragma unroll
  for (int m = 0; m < 4; ++m) {
    const int r = brow + r0 + m * 16;
#pragma unroll
    for (int n = 0; n < 4; ++n) {
      const int c = bcol + c0 + n * 16;
#pragma unroll
      for (int j = 0; j < 4; ++j) {
        unsigned short o = (c > r + j) ? (unsigned short)0xFF80  // -inf bf16
                                       : f2bf(acc[m][n][j]);
        S[(size_t)(r + j) * SEQQ + c] = o;
      }
    }
  }
}

// ---- row softmax over causal prefix, in place ----
__global__ __launch_bounds__(256) void softmax_causal(unsigned short* __restrict__ S) {
  const int row = blockIdx.x;
  const int L = ((row >> 7) + 1) << 7;  // multiple of 128 covering row+1
  unsigned short* Srow = S + (size_t)row * SEQQ;
  __shared__ float red[4];
  const int tid = threadIdx.x;
  const int lane = tid & 63, wave = tid >> 6;

  float x[16];
  bool have[2];
  float m = -3.0e38f;
#pragma unroll
  for (int it = 0; it < 2; ++it) {
    const int j = tid * 8 + it * 2048;
    have[it] = (j < L);
    if (have[it]) {
      const uint4 v = *reinterpret_cast<const uint4*>(Srow + j);
      const unsigned u[4] = {v.x, v.y, v.z, v.w};
#pragma unroll
      for (int q = 0; q < 4; ++q) {
        x[it * 8 + q * 2] = __builtin_bit_cast(float, u[q] << 16);
        x[it * 8 + q * 2 + 1] = __builtin_bit_cast(float, u[q] & 0xFFFF0000u);
      }
#pragma unroll
      for (int q = 0; q < 8; ++q) m = fmaxf(m, x[it * 8 + q]);
    }
  }
#pragma unroll
  for (int o = 32; o; o >>= 1) m = fmaxf(m, __shfl_xor(m, o));
  if (lane == 0) red[wave] = m;
  __syncthreads();
  m = fmaxf(fmaxf(red[0], red[1]), fmaxf(red[2], red[3]));
  __syncthreads();

  float sum = 0.f;
#pragma unroll
  for (int it = 0; it < 2; ++it)
    if (have[it]) {
#pragma unroll
      for (int q = 0; q < 8; ++q) {
        x[it * 8 + q] = __expf(x[it * 8 + q] - m);  // exp(-inf)=0 for masked
        sum += x[it * 8 + q];
      }
    }
#pragma unroll
  for (int o = 32; o; o >>= 1) sum += __shfl_xor(sum, o);
  if (lane == 0) red[wave] = sum;
  __syncthreads();
  sum = red[0] + red[1] + red[2] + red[3];
  const float inv = 1.0f / sum;

#pragma unroll
  for (int it = 0; it < 2; ++it)
    if (have[it]) {
      const int j = tid * 8 + it * 2048;
      unsigned u[4];
#pragma unroll
      for (int q = 0; q < 4; ++q) {
        u[q] = (unsigned)f2bf(x[it * 8 + q * 2] * inv) |
               ((unsigned)f2bf(x[it * 8 + q * 2 + 1] * inv) << 16);
      }
      *reinterpret_cast<uint4*>(Srow + j) = make_uint4(u[0], u[1], u[2], u[3]);
    }
}

// ---- partial-tile index helpers for split-K PV ----
// nc(bi) = (bi>>3)+1 chunks. Chunk 0 -> direct to out; chunks c>=1 -> partial
// tile rc = rcBase(bi) + (c-1), 8 bj tiles per rc, 64KB fp32 each.
__device__ __forceinline__ int pv_nc(int bi) { return (bi >> 3) + 1; }
__device__ __forceinline__ int pv_rcbase(int bi) {
  const int g = bi >> 3;  // 1..3 for bi>=8
  return (g == 1) ? (bi - 8) : (g == 2) ? 8 + (bi - 16) * 2 : 24 + (bi - 24) * 3;
}

// ---- PV split-K: out/partials = P @ Vt^T ----
__global__ __launch_bounds__(256, 3) void gemm_pv_split(const unsigned short* __restrict__ P,
                                                        const unsigned short* __restrict__ Vt,
                                                        float* __restrict__ O,
                                                        float* __restrict__ part) {
  const int bj = blockIdx.x, bi = blockIdx.y, ck = blockIdx.z;
  const int nc = pv_nc(bi);
  if (ck >= nc) return;
  const int steps = (bi + 1) * 4;               // K-steps of 32 elems
  const int W = (steps + nc - 1) / nc;
  const int s0 = ck * W;
  const int s1 = min(s0 + W, steps);
  if (s0 >= s1) return;

  GEMM_PREAMBLE();
  const int brow = bi * 128, bcol = bj * 128;
  GEMM_LOOP(P + (size_t)brow * SEQQ, SEQQ, Vt + (size_t)bcol * SEQQ, SEQQ, s0, s1);
  const int c0 = wc + (lane & 15);
  const int r0 = wr + ((lane >> 4) << 2);
  if (ck == 0) {
#pragma unroll
    for (int m = 0; m < 4; ++m) {
      const int r = brow + r0 + m * 16;
#pragma unroll
      for (int n = 0; n < 4; ++n) {
        const int c = bcol + c0 + n * 16;
#pragma unroll
        for (int j = 0; j < 4; ++j)
          O[(size_t)(r + j) * DDIM + c] = acc[m][n][j];
      }
    }
  } else {
    float* tile = part + ((size_t)(pv_rcbase(bi) + (ck - 1)) * 8 + bj) * 16384;
#pragma unroll
    for (int m = 0; m < 4; ++m) {
      const int lr = r0 + m * 16;
#pragma unroll
      for (int n = 0; n < 4; ++n) {
        const int lc = c0 + n * 16;
#pragma unroll
        for (int j = 0; j < 4; ++j)
          tile[(lr + j) * 128 + lc] = acc[m][n][j];
      }
    }
  }
}

// ---- add partial tiles into out rows >= 1024 ----
__global__ __launch_bounds__(256) void reduce_pv(float* __restrict__ O,
                                                 const float* __restrict__ part) {
  const int idx = blockIdx.x * 256 + threadIdx.x;   // one float4 per thread
  const int r = 1024 + (idx >> 8);                  // 256 float4s per row
  const int cc = (idx & 255) * 4;
  const int bi = r >> 7;
  const int nparts = pv_nc(bi) - 1;
  const int rcb = pv_rcbase(bi);
  const int bj = cc >> 7;
  const int lr = r & 127, lc = cc & 127;
  float4 acc = *reinterpret_cast<float4*>(O + (size_t)r * DDIM + cc);
  for (int k = 0; k < nparts; ++k) {
    const float4 p = *reinterpret_cast<const float4*>(
        part + ((size_t)(rcb + k) * 8 + bj) * 16384 + lr * 128 + lc);
    acc.x += p.x; acc.y += p.y; acc.z += p.z; acc.w += p.w;
  }
  *reinterpret_cast<float4*>(O + (size_t)r * DDIM + cc) = acc;
}

extern "C" void kernel_launch(void* const* d_in, const int* in_sizes, int n_in,
                              void* d_out, int out_size, void* d_ws, size_t ws_size,
                              hipStream_t stream) {
  (void)in_sizes; (void)n_in; (void)out_size; (void)ws_size;
  const float* x = (const float*)d_in[0];
  const float* Wq = (const float*)d_in[1];
  const float* Wk = (const float*)d_in[2];
  const float* Wv = (const float*)d_in[3];
  float* out = (float*)d_out;

  char* ws = (char*)d_ws;
  unsigned short* xb   = (unsigned short*)(ws);                        //  8 MB [4096,1024]
  unsigned short* Wcat = (unsigned short*)(ws + ((size_t)8 << 20));    //  6 MB [3072,1024]
  unsigned short* Qb   = (unsigned short*)(ws + ((size_t)14 << 20));   //  8 MB [4096,1024]
  unsigned short* Kb   = (unsigned short*)(ws + ((size_t)22 << 20));   //  8 MB [4096,1024]
  unsigned short* Vt   = (unsigned short*)(ws + ((size_t)30 << 20));   //  8 MB [1024,4096]
  unsigned short* S    = (unsigned short*)(ws + ((size_t)38 << 20));   // 32 MB [4096,4096]
  float* part = (float*)ws;  // 24 MB of partial tiles; reuses dead xb/Wcat/Qb/Kb region

  cvt_all<<<7168, 256, 0, stream>>>(x, Wq, Wk, Wv, xb, Wcat);
  gemm_qkv<<<dim3(24, 32), 256, 0, stream>>>(xb, Wcat, Qb, Kb, Vt);
  gemm_qkt<<<dim3(32, 32), 256, 0, stream>>>(Qb, Kb, S);
  softmax_causal<<<SEQQ, 256, 0, stream>>>(S);
  gemm_pv_split<<<dim3(8, 32, 4), 256, 0, stream>>>(S, Vt, out, part);
  reduce_pv<<<3072, 256, 0, stream>>>(out, part);
}

// Round 7
// 137.474 us; speedup vs baseline: 1.0043x; 1.0043x over previous
//
#include <hip/hip_runtime.h>
#include <hip/hip_bf16.h>
#include <cstdint>
#include <cstddef>

// SelfAttentionV2: x[4096,1024] fp32; Wq/Wk/Wv [1024,1024] fp32.
// out = softmax(causal((x Wq^T)(x Wk^T)^T / 32)) @ (x Wv^T), fp32 out.
//
// GEMM structure (all three GEMMs): 256x256 tile, 8 waves (512 thr, 2Mx4N),
// per-wave output 128x64 (acc[8][4] f32x4), BK=32, 3 LDS K-tile buffers
// (3 x 32KB = 96KB). Per K-tile: 2 phases, each
//   { ds_read frags (8 or 4 b128) | issue 2 global_load_lds for K-tile t+2
//     -> barrier -> lgkmcnt(0) -> setprio(1) 16 MFMA setprio(0) -> barrier }
// vmcnt(4) once per K-tile (counted, never 0 in steady state). Staging for
// t+2 targets buf (t+2)%3 != buf(t)%3, so there is NO write-after-read race
// by construction (reads of t-1's buffer completed before t's phases begin).
// LDS rows 64B; XOR swizzle byte ^= ((byte>>9)&1)<<5 applied to the global
// SOURCE on stage (global_load_lds writes linearly) and to ds_read addrs
// (same involution both sides; measured 0 bank conflicts in R2-R6).

#define SEQQ 4096
#define DDIM 1024

typedef __bf16 bf16x8 __attribute__((ext_vector_type(8)));
typedef float f32x4 __attribute__((ext_vector_type(4)));

__device__ __forceinline__ unsigned short f2bf(float f) {
  unsigned int u = __builtin_bit_cast(unsigned int, f);
  unsigned int r = u + 0x7FFFu + ((u >> 16) & 1u);  // RNE; -inf stays -inf
  return (unsigned short)(r >> 16);
}

__device__ __forceinline__ void gload_lds16(const void* g, void* lds) {
  __builtin_amdgcn_global_load_lds(
      (__attribute__((address_space(1))) void*)(uintptr_t)g,
      (__attribute__((address_space(3))) void*)(uintptr_t)lds, 16, 0, 0);
}

// ---- fused fp32 -> bf16 conversion (x, Wq*1/32, Wk, Wv) ----
__global__ __launch_bounds__(256) void cvt_all(const float* __restrict__ x,
                                               const float* __restrict__ Wq,
                                               const float* __restrict__ Wk,
                                               const float* __restrict__ Wv,
                                               unsigned short* __restrict__ xb,
                                               unsigned short* __restrict__ Wcat) {
  int b = blockIdx.x;
  const float* src;
  unsigned short* dst;
  float scale = 1.0f;
  if (b < 4096) {
    src = x; dst = xb;
  } else if (b < 5120) {
    src = Wq; dst = Wcat; scale = 0.03125f; b -= 4096;
  } else if (b < 6144) {
    src = Wk; dst = Wcat + (1u << 20); b -= 5120;
  } else {
    src = Wv; dst = Wcat + (2u << 20); b -= 6144;
  }
  const int i = (b * 256 + threadIdx.x) * 4;
  const float4 v = *reinterpret_cast<const float4*>(src + i);
  ushort4 o;
  o.x = f2bf(v.x * scale);
  o.y = f2bf(v.y * scale);
  o.z = f2bf(v.z * scale);
  o.w = f2bf(v.w * scale);
  *reinterpret_cast<ushort4*>(dst + i) = o;
}

// ---- 256x256 GEMM core ----
// LDS per operand per buffer: [256][32] bf16 = 16KB, rows 64B.
// Stage: half h (128 rows) per gload round; wave w covers rows h*128+w*16+(l>>2),
// LDS linear dest = bufbase + h*8192 + w*1024 (+ lane*16 by HW).
// Source col byte pre-swizzled: ((l&3)*16) ^ (((l>>5)&1)<<5)  [= row-bit3 XOR].

#define GEMM_PRE()                                                          \
  __shared__ unsigned short As[3][8192] __attribute__((aligned(16)));       \
  __shared__ unsigned short Bs[3][8192] __attribute__((aligned(16)));       \
  const int tid = threadIdx.x;                                              \
  const int wave = tid >> 6, lane = tid & 63;                               \
  const int wr = (wave >> 2) * 128, wc = (wave & 3) * 64;                   \
  f32x4 acc[8][4] = {};                                                     \
  int offA[8], offB[4];                                                     \
  {                                                                         \
    const int cb = (lane >> 4) * 16;                                        \
    const int rA = wr + (lane & 15);                                        \
    _Pragma("unroll")                                                       \
    for (int m = 0; m < 8; ++m) {                                           \
      int o = (rA + m * 16) * 64 + cb;                                      \
      offA[m] = o ^ (((o >> 9) & 1) << 5);                                  \
    }                                                                       \
    const int rB = wc + (lane & 15);                                        \
    _Pragma("unroll")                                                       \
    for (int n = 0; n < 4; ++n) {                                           \
      int o = (rB + n * 16) * 64 + cb;                                      \
      offB[n] = o ^ (((o >> 9) & 1) << 5);                                  \
    }                                                                       \
  }

#define GEMM_LOOP(ABASE, LDA, BBASE, LDB, S0, S1)                           \
  do {                                                                      \
    const int nt = (S1) - (S0);                                             \
    const char *pA0, *pA1, *pB0, *pB1;                                      \
    {                                                                       \
      const size_t srow = wave * 16 + (lane >> 2);                          \
      const int scb = ((lane & 3) * 16) ^ (((lane >> 5) & 1) << 5);         \
      pA0 = (const char*)(ABASE) + srow * ((size_t)(LDA) * 2) +             \
            (size_t)(S0) * 64 + scb;                                        \
      pA1 = pA0 + (size_t)128 * ((size_t)(LDA) * 2);                        \
      pB0 = (const char*)(BBASE) + srow * ((size_t)(LDB) * 2) +             \
            (size_t)(S0) * 64 + scb;                                        \
      pB1 = pB0 + (size_t)128 * ((size_t)(LDB) * 2);                        \
    }                                                                       \
    char* ldsA = (char*)&As[0][0];                                          \
    char* ldsB = (char*)&Bs[0][0];                                          \
    const int wofs = wave * 1024;                                           \
    gload_lds16(pA0, ldsA + wofs);                                          \
    gload_lds16(pA1, ldsA + 8192 + wofs);                                   \
    gload_lds16(pB0, ldsB + wofs);                                          \
    gload_lds16(pB1, ldsB + 8192 + wofs);                                   \
    pA0 += 64; pA1 += 64; pB0 += 64; pB1 += 64;                             \
    if (nt > 1) {                                                           \
      gload_lds16(pA0, ldsA + 16384 + wofs);                                \
      gload_lds16(pA1, ldsA + 16384 + 8192 + wofs);                         \
      gload_lds16(pB0, ldsB + 16384 + wofs);                                \
      gload_lds16(pB1, ldsB + 16384 + 8192 + wofs);                         \
      pA0 += 64; pA1 += 64; pB0 += 64; pB1 += 64;                           \
      asm volatile("s_waitcnt vmcnt(4)" ::: "memory");                      \
    } else {                                                                \
      asm volatile("s_waitcnt vmcnt(0)" ::: "memory");                      \
    }                                                                       \
    asm volatile("s_barrier" ::: "memory");                                 \
    int rb = 0;                                                             \
    for (int s = 0; s < nt; ++s) {                                          \
      const int bofs = rb * 16384;                                          \
      const int wb = (rb >= 1) ? rb - 1 : 2;                                \
      const int wofs2 = wb * 16384 + wofs;                                  \
      const bool pf = (s + 2 < nt);                                         \
      bf16x8 a[4], b[4];                                                    \
      /* ---- phase 0: m-frags 0..3, all B-frags ---- */                    \
      _Pragma("unroll")                                                     \
      for (int m = 0; m < 4; ++m)                                           \
        a[m] = *(const bf16x8*)(ldsA + bofs + offA[m]);                     \
      _Pragma("unroll")                                                     \
      for (int n = 0; n < 4; ++n)                                           \
        b[n] = *(const bf16x8*)(ldsB + bofs + offB[n]);                     \
      if (pf) {                                                             \
        gload_lds16(pA0, ldsA + wofs2);                                     \
        gload_lds16(pB0, ldsB + wofs2);                                     \
      }                                                                     \
      asm volatile("s_barrier" ::: "memory");                               \
      asm volatile("s_waitcnt lgkmcnt(0)" ::: "memory");                    \
      __builtin_amdgcn_s_setprio(1);                                        \
      _Pragma("unroll")                                                     \
      for (int m = 0; m < 4; ++m)                                           \
        _Pragma("unroll")                                                   \
        for (int n = 0; n < 4; ++n)                                         \
          acc[m][n] = __builtin_amdgcn_mfma_f32_16x16x32_bf16(              \
              a[m], b[n], acc[m][n], 0, 0, 0);                              \
      __builtin_amdgcn_s_setprio(0);                                        \
      asm volatile("s_barrier" ::: "memory");                               \
      /* ---- phase 1: m-frags 4..7, B reused from regs ---- */             \
      _Pragma("unroll")                                                     \
      for (int m = 0; m < 4; ++m)                                           \
        a[m] = *(const bf16x8*)(ldsA + bofs + offA[4 + m]);                 \
      if (pf) {                                                             \
        gload_lds16(pA1, ldsA + wofs2 + 8192);                              \
        gload_lds16(pB1, ldsB + wofs2 + 8192);                              \
        pA0 += 64; pA1 += 64; pB0 += 64; pB1 += 64;                         \
        asm volatile("s_waitcnt vmcnt(4)" ::: "memory");                    \
      } else {                                                              \
        asm volatile("s_waitcnt vmcnt(0)" ::: "memory");                    \
      }                                                                     \
      asm volatile("s_barrier" ::: "memory");                               \
      asm volatile("s_waitcnt lgkmcnt(0)" ::: "memory");                    \
      __builtin_amdgcn_s_setprio(1);                                        \
      _Pragma("unroll")                                                     \
      for (int m = 0; m < 4; ++m)                                           \
        _Pragma("unroll")                                                   \
        for (int n = 0; n < 4; ++n)                                         \
          acc[4 + m][n] = __builtin_amdgcn_mfma_f32_16x16x32_bf16(          \
              a[m], b[n], acc[4 + m][n], 0, 0, 0);                          \
      __builtin_amdgcn_s_setprio(0);                                        \
      asm volatile("s_barrier" ::: "memory");                               \
      rb = (rb == 2) ? 0 : rb + 1;                                          \
    }                                                                       \
  } while (0)

// ---- QKV: C[4096,3072] = xb @ Wcat^T; Q,K row-major; V transposed ----
__global__ __launch_bounds__(512, 2) void gemm_qkv(const unsigned short* __restrict__ X,
                                                   const unsigned short* __restrict__ W,
                                                   unsigned short* __restrict__ Qb,
                                                   unsigned short* __restrict__ Kb,
                                                   unsigned short* __restrict__ Vt) {
  GEMM_PRE();
  const int brow = blockIdx.y * 256, bcol = blockIdx.x * 256;
  GEMM_LOOP(X + (size_t)brow * DDIM, DDIM, W + (size_t)bcol * DDIM, DDIM, 0, 32);
  const int region = bcol >> 10;  // 0=Q 1=K 2=V
  const int lcol = bcol & 1023;
  const int c0 = wc + (lane & 15);
  const int r0 = wr + ((lane >> 4) << 2);
  if (region < 2) {
    unsigned short* dst = (region == 0) ? Qb : Kb;
#pragma unroll
    for (int m = 0; m < 8; ++m) {
      const int r = brow + r0 + m * 16;
#pragma unroll
      for (int n = 0; n < 4; ++n) {
        const int c = lcol + c0 + n * 16;
#pragma unroll
        for (int j = 0; j < 4; ++j)
          dst[(size_t)(r + j) * DDIM + c] = f2bf(acc[m][n][j]);
      }
    }
  } else {
#pragma unroll
    for (int m = 0; m < 8; ++m) {
      const int r = brow + r0 + m * 16;
#pragma unroll
      for (int n = 0; n < 4; ++n) {
        const int c = lcol + c0 + n * 16;
        ushort4 pk;
        pk.x = f2bf(acc[m][n][0]);
        pk.y = f2bf(acc[m][n][1]);
        pk.z = f2bf(acc[m][n][2]);
        pk.w = f2bf(acc[m][n][3]);
        *reinterpret_cast<ushort4*>(Vt + (size_t)c * SEQQ + r) = pk;
      }
    }
  }
}

// ---- QK^T: S = Qb @ Kb^T, lower-triangle 256-tiles, causal mask ----
__global__ __launch_bounds__(512, 2) void gemm_qkt(const unsigned short* __restrict__ Qb,
                                                   const unsigned short* __restrict__ Kb,
                                                   unsigned short* __restrict__ S) {
  const int bi = blockIdx.y, bj = blockIdx.x;
  if (bj > bi) return;
  GEMM_PRE();
  const int brow = bi * 256, bcol = bj * 256;
  GEMM_LOOP(Qb + (size_t)brow * DDIM, DDIM, Kb + (size_t)bcol * DDIM, DDIM, 0, 32);
  const int c0 = wc + (lane & 15);
  const int r0 = wr + ((lane >> 4) << 2);
#pragma unroll
  for (int m = 0; m < 8; ++m) {
    const int r = brow + r0 + m * 16;
#pragma unroll
    for (int n = 0; n < 4; ++n) {
      const int c = bcol + c0 + n * 16;
#pragma unroll
      for (int j = 0; j < 4; ++j) {
        unsigned short o = (c > r + j) ? (unsigned short)0xFF80  // -inf bf16
                                       : f2bf(acc[m][n][j]);
        S[(size_t)(r + j) * SEQQ + c] = o;
      }
    }
  }
}

// ---- row softmax over causal prefix (256-padded), in place ----
__global__ __launch_bounds__(256) void softmax_causal(unsigned short* __restrict__ S) {
  const int row = blockIdx.x;
  const int L = ((row >> 8) + 1) << 8;  // 256-padded: matches PV K-extent
  unsigned short* Srow = S + (size_t)row * SEQQ;
  __shared__ float red[4];
  const int tid = threadIdx.x;
  const int lane = tid & 63, wave = tid >> 6;

  float x[16];
  bool have[2];
  float m = -3.0e38f;
#pragma unroll
  for (int it = 0; it < 2; ++it) {
    const int j = tid * 8 + it * 2048;
    have[it] = (j < L);
    if (have[it]) {
      const uint4 v = *reinterpret_cast<const uint4*>(Srow + j);
      const unsigned u[4] = {v.x, v.y, v.z, v.w};
#pragma unroll
      for (int q = 0; q < 4; ++q) {
        x[it * 8 + q * 2] = __builtin_bit_cast(float, u[q] << 16);
        x[it * 8 + q * 2 + 1] = __builtin_bit_cast(float, u[q] & 0xFFFF0000u);
      }
#pragma unroll
      for (int q = 0; q < 8; ++q) m = fmaxf(m, x[it * 8 + q]);
    }
  }
#pragma unroll
  for (int o = 32; o; o >>= 1) m = fmaxf(m, __shfl_xor(m, o));
  if (lane == 0) red[wave] = m;
  __syncthreads();
  m = fmaxf(fmaxf(red[0], red[1]), fmaxf(red[2], red[3]));
  __syncthreads();

  float sum = 0.f;
#pragma unroll
  for (int it = 0; it < 2; ++it)
    if (have[it]) {
#pragma unroll
      for (int q = 0; q < 8; ++q) {
        x[it * 8 + q] = __expf(x[it * 8 + q] - m);  // exp(-inf)=0 for masked
        sum += x[it * 8 + q];
      }
    }
#pragma unroll
  for (int o = 32; o; o >>= 1) sum += __shfl_xor(sum, o);
  if (lane == 0) red[wave] = sum;
  __syncthreads();
  sum = red[0] + red[1] + red[2] + red[3];
  const float inv = 1.0f / sum;

#pragma unroll
  for (int it = 0; it < 2; ++it)
    if (have[it]) {
      const int j = tid * 8 + it * 2048;
      unsigned u[4];
#pragma unroll
      for (int q = 0; q < 4; ++q) {
        u[q] = (unsigned)f2bf(x[it * 8 + q * 2] * inv) |
               ((unsigned)f2bf(x[it * 8 + q * 2 + 1] * inv) << 16);
      }
      *reinterpret_cast<uint4*>(Srow + j) = make_uint4(u[0], u[1], u[2], u[3]);
    }
}

// ---- split-K helpers for PV (256-row blocks bi=0..15) ----
// nc(bi) = (bi>>2)+1 chunks (1..4). rcbase = sum_{b<bi} (b>>2).
__device__ __forceinline__ int pv_nc(int bi) { return (bi >> 2) + 1; }
__device__ __forceinline__ int pv_rcbase(int bi) {
  const int g = bi >> 2, r = bi & 3;
  return 2 * g * (g - 1) + r * g;
}

// ---- PV: out/partials = P @ Vt^T, causal K-range, split-K ----
__global__ __launch_bounds__(512, 2) void gemm_pv_split(const unsigned short* __restrict__ P,
                                                        const unsigned short* __restrict__ Vt,
                                                        float* __restrict__ O,
                                                        float* __restrict__ part) {
  const int bj = blockIdx.x, bi = blockIdx.y, ck = blockIdx.z;
  const int nc = pv_nc(bi);
  if (ck >= nc) return;
  const int kt = (bi + 1) * 8;                  // K-tiles of 32 elems
  const int W = (kt + nc - 1) / nc;
  const int s0 = ck * W;
  const int s1 = min(s0 + W, kt);
  if (s0 >= s1) return;

  GEMM_PRE();
  const int brow = bi * 256, bcol = bj * 256;
  GEMM_LOOP(P + (size_t)brow * SEQQ, SEQQ, Vt + (size_t)bcol * SEQQ, SEQQ, s0, s1);
  const int c0 = wc + (lane & 15);
  const int r0 = wr + ((lane >> 4) << 2);
  if (ck == 0) {
#pragma unroll
    for (int m = 0; m < 8; ++m) {
      const int r = brow + r0 + m * 16;
#pragma unroll
      for (int n = 0; n < 4; ++n) {
        const int c = bcol + c0 + n * 16;
#pragma unroll
        for (int j = 0; j < 4; ++j)
          O[(size_t)(r + j) * DDIM + c] = acc[m][n][j];
      }
    }
  } else {
    float* tile = part + ((size_t)(pv_rcbase(bi) + (ck - 1)) * 4 + bj) * 65536;
#pragma unroll
    for (int m = 0; m < 8; ++m) {
      const int lr = r0 + m * 16;
#pragma unroll
      for (int n = 0; n < 4; ++n) {
        const int lc = c0 + n * 16;
#pragma unroll
        for (int j = 0; j < 4; ++j)
          tile[(lr + j) * 256 + lc] = acc[m][n][j];
      }
    }
  }
}

// ---- add partial tiles into out rows >= 1024 ----
__global__ __launch_bounds__(256) void reduce_pv(float* __restrict__ O,
                                                 const float* __restrict__ part) {
  const int idx = blockIdx.x * 256 + threadIdx.x;   // one float4 per thread
  const int r = 1024 + (idx >> 8);                  // 256 float4s per row
  const int cc = (idx & 255) * 4;
  const int bi = r >> 8;
  const int nparts = bi >> 2;                       // nc-1
  const int rcb = pv_rcbase(bi);
  const int bj = cc >> 8;
  const int lr = r & 255, lc = cc & 255;
  float4 acc = *reinterpret_cast<float4*>(O + (size_t)r * DDIM + cc);
  for (int k = 0; k < nparts; ++k) {
    const float4 p = *reinterpret_cast<const float4*>(
        part + ((size_t)(rcb + k) * 4 + bj) * 65536 + lr * 256 + lc);
    acc.x += p.x; acc.y += p.y; acc.z += p.z; acc.w += p.w;
  }
  *reinterpret_cast<float4*>(O + (size_t)r * DDIM + cc) = acc;
}

extern "C" void kernel_launch(void* const* d_in, const int* in_sizes, int n_in,
                              void* d_out, int out_size, void* d_ws, size_t ws_size,
                              hipStream_t stream) {
  (void)in_sizes; (void)n_in; (void)out_size; (void)ws_size;
  const float* x = (const float*)d_in[0];
  const float* Wq = (const float*)d_in[1];
  const float* Wk = (const float*)d_in[2];
  const float* Wv = (const float*)d_in[3];
  float* out = (float*)d_out;

  char* ws = (char*)d_ws;
  unsigned short* xb   = (unsigned short*)(ws);                        //  8 MB [4096,1024]
  unsigned short* Wcat = (unsigned short*)(ws + ((size_t)8 << 20));    //  6 MB [3072,1024]
  unsigned short* Qb   = (unsigned short*)(ws + ((size_t)14 << 20));   //  8 MB [4096,1024]
  unsigned short* Kb   = (unsigned short*)(ws + ((size_t)22 << 20));   //  8 MB [4096,1024]
  unsigned short* Vt   = (unsigned short*)(ws + ((size_t)30 << 20));   //  8 MB [1024,4096]
  unsigned short* S    = (unsigned short*)(ws + ((size_t)38 << 20));   // 32 MB [4096,4096]
  float* part = (float*)ws;  // 24 MB fp32 partials; reuses dead xb/Wcat/Qb/Kb region

  cvt_all<<<7168, 256, 0, stream>>>(x, Wq, Wk, Wv, xb, Wcat);
  gemm_qkv<<<dim3(12, 16), 512, 0, stream>>>(xb, Wcat, Qb, Kb, Vt);
  gemm_qkt<<<dim3(16, 16), 512, 0, stream>>>(Qb, Kb, S);
  softmax_causal<<<SEQQ, 256, 0, stream>>>(S);
  gemm_pv_split<<<dim3(4, 16, 4), 512, 0, stream>>>(S, Vt, out, part);
  reduce_pv<<<3072, 256, 0, stream>>>(out, part);
}

// Round 8
// 127.478 us; speedup vs baseline: 1.0830x; 1.0784x over previous
//
#include <hip/hip_runtime.h>
#include <hip/hip_bf16.h>
#include <cstdint>
#include <cstddef>

// SelfAttentionV2: x[4096,1024] fp32; Wq/Wk/Wv [1024,1024] fp32.
// out = softmax(causal((x Wq^T)(x Wk^T)^T / 32)) @ (x Wv^T), fp32 out.
//
// GEMM structure: 256x256 tile, 8 waves (512 thr, 2Mx4N), per-wave out 128x64,
// BK=32, 3 LDS K-tile ring buffers (96KB). ONE barrier per K-tile:
//   { 12 ds_read (a[8],b[4]) | 4 global_load_lds for tile s+2 into buf(s+2)%3
//     -> lgkmcnt(0) -> vmcnt(4) -> s_barrier -> setprio(1) 32 MFMA setprio(0) }
// Hazard proof: before barrier(s), every wave drained its own ds_reads
// (lgkmcnt 0) and tile s+1's stages landed (vmcnt 4: 8 outstanding - 4 of
// step s = step s-1's 4). After barrier(s), stages into buf(s+2) (= old
// buf(s-1)) are safe: no wave has in-flight reads of it. MFMA region has no
// trailing barrier -> waves free-run; LDS reads/stages overlap MFMA across
// waves (32 MFMA per barrier, AITER-style density).
// LDS rows 64B; XOR swizzle byte ^= ((byte>>9)&1)<<5 applied to the global
// SOURCE on stage (global_load_lds writes linearly) and to ds_read addrs
// (same involution both sides; 0 bank conflicts measured R2-R7).

#define SEQQ 4096
#define DDIM 1024

typedef __bf16 bf16x8 __attribute__((ext_vector_type(8)));
typedef float f32x4 __attribute__((ext_vector_type(4)));

__device__ __forceinline__ unsigned short f2bf(float f) {
  unsigned int u = __builtin_bit_cast(unsigned int, f);
  unsigned int r = u + 0x7FFFu + ((u >> 16) & 1u);  // RNE; -inf stays -inf
  return (unsigned short)(r >> 16);
}

__device__ __forceinline__ void gload_lds16(const void* g, void* lds) {
  __builtin_amdgcn_global_load_lds(
      (__attribute__((address_space(1))) void*)(uintptr_t)g,
      (__attribute__((address_space(3))) void*)(uintptr_t)lds, 16, 0, 0);
}

// ---- fused fp32 -> bf16 conversion (x, Wq*1/32, Wk, Wv) ----
__global__ __launch_bounds__(256) void cvt_all(const float* __restrict__ x,
                                               const float* __restrict__ Wq,
                                               const float* __restrict__ Wk,
                                               const float* __restrict__ Wv,
                                               unsigned short* __restrict__ xb,
                                               unsigned short* __restrict__ Wcat) {
  int b = blockIdx.x;
  const float* src;
  unsigned short* dst;
  float scale = 1.0f;
  if (b < 4096) {
    src = x; dst = xb;
  } else if (b < 5120) {
    src = Wq; dst = Wcat; scale = 0.03125f; b -= 4096;
  } else if (b < 6144) {
    src = Wk; dst = Wcat + (1u << 20); b -= 5120;
  } else {
    src = Wv; dst = Wcat + (2u << 20); b -= 6144;
  }
  const int i = (b * 256 + threadIdx.x) * 4;
  const float4 v = *reinterpret_cast<const float4*>(src + i);
  ushort4 o;
  o.x = f2bf(v.x * scale);
  o.y = f2bf(v.y * scale);
  o.z = f2bf(v.z * scale);
  o.w = f2bf(v.w * scale);
  *reinterpret_cast<ushort4*>(dst + i) = o;
}

// ---- 256x256 GEMM core: LDS [3 buf][256 r][32 c] bf16 per operand ----
#define GEMM_PRE()                                                          \
  __shared__ unsigned short As[3][8192] __attribute__((aligned(16)));       \
  __shared__ unsigned short Bs[3][8192] __attribute__((aligned(16)));       \
  const int tid = threadIdx.x;                                              \
  const int wave = tid >> 6, lane = tid & 63;                               \
  const int wr = (wave >> 2) * 128, wc = (wave & 3) * 64;                   \
  f32x4 acc[8][4] = {};                                                     \
  int offA[8], offB[4];                                                     \
  {                                                                         \
    const int cb = (lane >> 4) * 16;                                        \
    const int rA = wr + (lane & 15);                                        \
    _Pragma("unroll")                                                       \
    for (int m = 0; m < 8; ++m) {                                           \
      int o = (rA + m * 16) * 64 + cb;                                      \
      offA[m] = o ^ (((o >> 9) & 1) << 5);                                  \
    }                                                                       \
    const int rB = wc + (lane & 15);                                        \
    _Pragma("unroll")                                                       \
    for (int n = 0; n < 4; ++n) {                                           \
      int o = (rB + n * 16) * 64 + cb;                                      \
      offB[n] = o ^ (((o >> 9) & 1) << 5);                                  \
    }                                                                       \
  }

#define GEMM_LOOP(ABASE, LDA, BBASE, LDB, S0, S1)                           \
  do {                                                                      \
    const int nt = (S1) - (S0);                                             \
    const char *pA0, *pA1, *pB0, *pB1;                                      \
    {                                                                       \
      const size_t srow = wave * 16 + (lane >> 2);                          \
      const int scb = ((lane & 3) * 16) ^ (((lane >> 5) & 1) << 5);         \
      pA0 = (const char*)(ABASE) + srow * ((size_t)(LDA) * 2) +             \
            (size_t)(S0) * 64 + scb;                                        \
      pA1 = pA0 + (size_t)128 * ((size_t)(LDA) * 2);                        \
      pB0 = (const char*)(BBASE) + srow * ((size_t)(LDB) * 2) +             \
            (size_t)(S0) * 64 + scb;                                        \
      pB1 = pB0 + (size_t)128 * ((size_t)(LDB) * 2);                        \
    }                                                                       \
    char* ldsA = (char*)&As[0][0];                                          \
    char* ldsB = (char*)&Bs[0][0];                                          \
    const int wofs = wave * 1024;                                           \
    gload_lds16(pA0, ldsA + wofs);                                          \
    gload_lds16(pA1, ldsA + 8192 + wofs);                                   \
    gload_lds16(pB0, ldsB + wofs);                                          \
    gload_lds16(pB1, ldsB + 8192 + wofs);                                   \
    pA0 += 64; pA1 += 64; pB0 += 64; pB1 += 64;                             \
    if (nt > 1) {                                                           \
      gload_lds16(pA0, ldsA + 16384 + wofs);                                \
      gload_lds16(pA1, ldsA + 16384 + 8192 + wofs);                         \
      gload_lds16(pB0, ldsB + 16384 + wofs);                                \
      gload_lds16(pB1, ldsB + 16384 + 8192 + wofs);                         \
      pA0 += 64; pA1 += 64; pB0 += 64; pB1 += 64;                           \
      asm volatile("s_waitcnt vmcnt(4)" ::: "memory");                      \
    } else {                                                                \
      asm volatile("s_waitcnt vmcnt(0)" ::: "memory");                      \
    }                                                                       \
    asm volatile("s_barrier" ::: "memory");                                 \
    int rb = 0;                                                             \
    for (int s = 0; s < nt; ++s) {                                          \
      const int bofs = rb * 16384;                                          \
      bf16x8 a[8], b[4];                                                    \
      _Pragma("unroll")                                                     \
      for (int m = 0; m < 8; ++m)                                           \
        a[m] = *(const bf16x8*)(ldsA + bofs + offA[m]);                     \
      _Pragma("unroll")                                                     \
      for (int n = 0; n < 4; ++n)                                           \
        b[n] = *(const bf16x8*)(ldsB + bofs + offB[n]);                     \
      if (s + 2 < nt) {                                                     \
        const int wofs2 = ((rb >= 1) ? rb - 1 : 2) * 16384 + wofs;          \
        gload_lds16(pA0, ldsA + wofs2);                                     \
        gload_lds16(pA1, ldsA + wofs2 + 8192);                              \
        gload_lds16(pB0, ldsB + wofs2);                                     \
        gload_lds16(pB1, ldsB + wofs2 + 8192);                              \
        pA0 += 64; pA1 += 64; pB0 += 64; pB1 += 64;                         \
        asm volatile("s_waitcnt lgkmcnt(0)" ::: "memory");                  \
        asm volatile("s_waitcnt vmcnt(4)" ::: "memory");                    \
      } else if (s + 1 < nt) {                                              \
        asm volatile("s_waitcnt lgkmcnt(0)" ::: "memory");                  \
        asm volatile("s_waitcnt vmcnt(0)" ::: "memory");                    \
      } else {                                                              \
        asm volatile("s_waitcnt lgkmcnt(0)" ::: "memory");                  \
      }                                                                     \
      asm volatile("s_barrier" ::: "memory");                               \
      __builtin_amdgcn_s_setprio(1);                                        \
      _Pragma("unroll")                                                     \
      for (int m = 0; m < 8; ++m)                                           \
        _Pragma("unroll")                                                   \
        for (int n = 0; n < 4; ++n)                                         \
          acc[m][n] = __builtin_amdgcn_mfma_f32_16x16x32_bf16(              \
              a[m], b[n], acc[m][n], 0, 0, 0);                              \
      __builtin_amdgcn_s_setprio(0);                                        \
      rb = (rb == 2) ? 0 : rb + 1;                                          \
    }                                                                       \
  } while (0)

// ---- QKV: C[4096,3072] = xb @ Wcat^T; Q,K row-major; V transposed ----
__global__ __launch_bounds__(512, 1) void gemm_qkv(const unsigned short* __restrict__ X,
                                                   const unsigned short* __restrict__ W,
                                                   unsigned short* __restrict__ Qb,
                                                   unsigned short* __restrict__ Kb,
                                                   unsigned short* __restrict__ Vt) {
  GEMM_PRE();
  const int brow = blockIdx.y * 256, bcol = blockIdx.x * 256;
  GEMM_LOOP(X + (size_t)brow * DDIM, DDIM, W + (size_t)bcol * DDIM, DDIM, 0, 32);
  const int region = bcol >> 10;  // 0=Q 1=K 2=V
  const int lcol = bcol & 1023;
  const int c0 = wc + (lane & 15);
  const int r0 = wr + ((lane >> 4) << 2);
  if (region < 2) {
    unsigned short* dst = (region == 0) ? Qb : Kb;
#pragma unroll
    for (int m = 0; m < 8; ++m) {
      const int r = brow + r0 + m * 16;
#pragma unroll
      for (int n = 0; n < 4; ++n) {
        const int c = lcol + c0 + n * 16;
#pragma unroll
        for (int j = 0; j < 4; ++j)
          dst[(size_t)(r + j) * DDIM + c] = f2bf(acc[m][n][j]);
      }
    }
  } else {
#pragma unroll
    for (int m = 0; m < 8; ++m) {
      const int r = brow + r0 + m * 16;
#pragma unroll
      for (int n = 0; n < 4; ++n) {
        const int c = lcol + c0 + n * 16;
        ushort4 pk;
        pk.x = f2bf(acc[m][n][0]);
        pk.y = f2bf(acc[m][n][1]);
        pk.z = f2bf(acc[m][n][2]);
        pk.w = f2bf(acc[m][n][3]);
        *reinterpret_cast<ushort4*>(Vt + (size_t)c * SEQQ + r) = pk;
      }
    }
  }
}

// ---- QK^T: S = Qb @ Kb^T, lower-triangle 256-tiles, causal mask ----
__global__ __launch_bounds__(512, 1) void gemm_qkt(const unsigned short* __restrict__ Qb,
                                                   const unsigned short* __restrict__ Kb,
                                                   unsigned short* __restrict__ S) {
  const int bi = blockIdx.y, bj = blockIdx.x;
  if (bj > bi) return;
  GEMM_PRE();
  const int brow = bi * 256, bcol = bj * 256;
  GEMM_LOOP(Qb + (size_t)brow * DDIM, DDIM, Kb + (size_t)bcol * DDIM, DDIM, 0, 32);
  const int c0 = wc + (lane & 15);
  const int r0 = wr + ((lane >> 4) << 2);
#pragma unroll
  for (int m = 0; m < 8; ++m) {
    const int r = brow + r0 + m * 16;
#pragma unroll
    for (int n = 0; n < 4; ++n) {
      const int c = bcol + c0 + n * 16;
#pragma unroll
      for (int j = 0; j < 4; ++j) {
        unsigned short o = (c > r + j) ? (unsigned short)0xFF80  // -inf bf16
                                       : f2bf(acc[m][n][j]);
        S[(size_t)(r + j) * SEQQ + c] = o;
      }
    }
  }
}

// ---- row softmax over causal prefix (256-padded), in place ----
__global__ __launch_bounds__(256) void softmax_causal(unsigned short* __restrict__ S) {
  const int row = blockIdx.x;
  const int L = ((row >> 8) + 1) << 8;  // 256-padded: matches PV K-extent
  unsigned short* Srow = S + (size_t)row * SEQQ;
  __shared__ float red[4];
  const int tid = threadIdx.x;
  const int lane = tid & 63, wave = tid >> 6;

  float x[16];
  bool have[2];
  float m = -3.0e38f;
#pragma unroll
  for (int it = 0; it < 2; ++it) {
    const int j = tid * 8 + it * 2048;
    have[it] = (j < L);
    if (have[it]) {
      const uint4 v = *reinterpret_cast<const uint4*>(Srow + j);
      const unsigned u[4] = {v.x, v.y, v.z, v.w};
#pragma unroll
      for (int q = 0; q < 4; ++q) {
        x[it * 8 + q * 2] = __builtin_bit_cast(float, u[q] << 16);
        x[it * 8 + q * 2 + 1] = __builtin_bit_cast(float, u[q] & 0xFFFF0000u);
      }
#pragma unroll
      for (int q = 0; q < 8; ++q) m = fmaxf(m, x[it * 8 + q]);
    }
  }
#pragma unroll
  for (int o = 32; o; o >>= 1) m = fmaxf(m, __shfl_xor(m, o));
  if (lane == 0) red[wave] = m;
  __syncthreads();
  m = fmaxf(fmaxf(red[0], red[1]), fmaxf(red[2], red[3]));
  __syncthreads();

  float sum = 0.f;
#pragma unroll
  for (int it = 0; it < 2; ++it)
    if (have[it]) {
#pragma unroll
      for (int q = 0; q < 8; ++q) {
        x[it * 8 + q] = __expf(x[it * 8 + q] - m);  // exp(-inf)=0 for masked
        sum += x[it * 8 + q];
      }
    }
#pragma unroll
  for (int o = 32; o; o >>= 1) sum += __shfl_xor(sum, o);
  if (lane == 0) red[wave] = sum;
  __syncthreads();
  sum = red[0] + red[1] + red[2] + red[3];
  const float inv = 1.0f / sum;

#pragma unroll
  for (int it = 0; it < 2; ++it)
    if (have[it]) {
      const int j = tid * 8 + it * 2048;
      unsigned u[4];
#pragma unroll
      for (int q = 0; q < 4; ++q) {
        u[q] = (unsigned)f2bf(x[it * 8 + q * 2] * inv) |
               ((unsigned)f2bf(x[it * 8 + q * 2 + 1] * inv) << 16);
      }
      *reinterpret_cast<uint4*>(Srow + j) = make_uint4(u[0], u[1], u[2], u[3]);
    }
}

// ---- split-K helpers for PV (256-row blocks bi=0..15) ----
__device__ __forceinline__ int pv_nc(int bi) { return (bi >> 2) + 1; }
__device__ __forceinline__ int pv_rcbase(int bi) {
  const int g = bi >> 2, r = bi & 3;
  return 2 * g * (g - 1) + r * g;
}

// ---- PV: out/partials = P @ Vt^T, causal K-range, split-K ----
__global__ __launch_bounds__(512, 1) void gemm_pv_split(const unsigned short* __restrict__ P,
                                                        const unsigned short* __restrict__ Vt,
                                                        float* __restrict__ O,
                                                        float* __restrict__ part) {
  const int bj = blockIdx.x, bi = blockIdx.y, ck = blockIdx.z;
  const int nc = pv_nc(bi);
  if (ck >= nc) return;
  const int kt = (bi + 1) * 8;                  // K-tiles of 32 elems
  const int W = (kt + nc - 1) / nc;
  const int s0 = ck * W;
  const int s1 = min(s0 + W, kt);
  if (s0 >= s1) return;

  GEMM_PRE();
  const int brow = bi * 256, bcol = bj * 256;
  GEMM_LOOP(P + (size_t)brow * SEQQ, SEQQ, Vt + (size_t)bcol * SEQQ, SEQQ, s0, s1);
  const int c0 = wc + (lane & 15);
  const int r0 = wr + ((lane >> 4) << 2);
  if (ck == 0) {
#pragma unroll
    for (int m = 0; m < 8; ++m) {
      const int r = brow + r0 + m * 16;
#pragma unroll
      for (int n = 0; n < 4; ++n) {
        const int c = bcol + c0 + n * 16;
#pragma unroll
        for (int j = 0; j < 4; ++j)
          O[(size_t)(r + j) * DDIM + c] = acc[m][n][j];
      }
    }
  } else {
    float* tile = part + ((size_t)(pv_rcbase(bi) + (ck - 1)) * 4 + bj) * 65536;
#pragma unroll
    for (int m = 0; m < 8; ++m) {
      const int lr = r0 + m * 16;
#pragma unroll
      for (int n = 0; n < 4; ++n) {
        const int lc = c0 + n * 16;
#pragma unroll
        for (int j = 0; j < 4; ++j)
          tile[(lr + j) * 256 + lc] = acc[m][n][j];
      }
    }
  }
}

// ---- add partial tiles into out rows >= 1024 ----
__global__ __launch_bounds__(256) void reduce_pv(float* __restrict__ O,
                                                 const float* __restrict__ part) {
  const int idx = blockIdx.x * 256 + threadIdx.x;   // one float4 per thread
  const int r = 1024 + (idx >> 8);                  // 256 float4s per row
  const int cc = (idx & 255) * 4;
  const int bi = r >> 8;
  const int nparts = bi >> 2;                       // nc-1
  const int rcb = pv_rcbase(bi);
  const int bj = cc >> 8;
  const int lr = r & 255, lc = cc & 255;
  float4 acc = *reinterpret_cast<float4*>(O + (size_t)r * DDIM + cc);
  for (int k = 0; k < nparts; ++k) {
    const float4 p = *reinterpret_cast<const float4*>(
        part + ((size_t)(rcb + k) * 4 + bj) * 65536 + lr * 256 + lc);
    acc.x += p.x; acc.y += p.y; acc.z += p.z; acc.w += p.w;
  }
  *reinterpret_cast<float4*>(O + (size_t)r * DDIM + cc) = acc;
}

extern "C" void kernel_launch(void* const* d_in, const int* in_sizes, int n_in,
                              void* d_out, int out_size, void* d_ws, size_t ws_size,
                              hipStream_t stream) {
  (void)in_sizes; (void)n_in; (void)out_size; (void)ws_size;
  const float* x = (const float*)d_in[0];
  const float* Wq = (const float*)d_in[1];
  const float* Wk = (const float*)d_in[2];
  const float* Wv = (const float*)d_in[3];
  float* out = (float*)d_out;

  char* ws = (char*)d_ws;
  unsigned short* xb   = (unsigned short*)(ws);                        //  8 MB [4096,1024]
  unsigned short* Wcat = (unsigned short*)(ws + ((size_t)8 << 20));    //  6 MB [3072,1024]
  unsigned short* Qb   = (unsigned short*)(ws + ((size_t)14 << 20));   //  8 MB [4096,1024]
  unsigned short* Kb   = (unsigned short*)(ws + ((size_t)22 << 20));   //  8 MB [4096,1024]
  unsigned short* Vt   = (unsigned short*)(ws + ((size_t)30 << 20));   //  8 MB [1024,4096]
  unsigned short* S    = (unsigned short*)(ws + ((size_t)38 << 20));   // 32 MB [4096,4096]
  float* part = (float*)ws;  // 24 MB fp32 partials; reuses dead xb/Wcat/Qb/Kb region

  cvt_all<<<7168, 256, 0, stream>>>(x, Wq, Wk, Wv, xb, Wcat);
  gemm_qkv<<<dim3(12, 16), 512, 0, stream>>>(xb, Wcat, Qb, Kb, Vt);
  gemm_qkt<<<dim3(16, 16), 512, 0, stream>>>(Qb, Kb, S);
  softmax_causal<<<SEQQ, 256, 0, stream>>>(S);
  gemm_pv_split<<<dim3(4, 16, 4), 512, 0, stream>>>(S, Vt, out, part);
  reduce_pv<<<3072, 256, 0, stream>>>(out, part);
}